// Round 12
// baseline (174.940 us; speedup 1.0000x reference)
//
#include <hip/hip_runtime.h>
#include <hip/hip_bf16.h>
#include <stdint.h>

// BSpline KAN layer: out[b,o] = sum_{i,k} bases(tanh(x[b,i]))[k] * C[i,o,k]
// == GEMM M=8192, N=512, K=4096 with generated A. bf16 MFMA path.
// History:
//  R10 57.4us materialized A. R11 62.2: 64x64 tiles. R12 46.5us: counted
//      vmcnt 4-deep (+25%), 1 block/CU. R13 48.3us NEUTRAL: shrank LDS for
//      2 blocks/CU but GRID IS 256 = 1 block/CU regardless. Lesson:
//      occupancy = min(grid/CU, resources).
//  R12 phase budget re-audit: 1744 cyc = ds_reads 768 + STAGE LDS-WRITES
//      ~384 (global_load_lds transits the LDS port) + MFMA 620/SIMD overlap
//      + residual. Port ~66% busy — B is 2/3 of the port traffic.
//  R14: B bypasses LDS: per-wave global->reg prefetch 1 phase ahead (R2's
//      verified pattern + counted vmcnt + sched_barrier pin, R4 lesson).
//      A stays LDS (cross-wave sharing): 4 bufs x 2 groups x 8 KB = 64 KB,
//      staged 2 ahead. Waits: top vmcnt(6) [own A(t) done BEFORE barrier --
//      cross-wave requirement]; post-issue vmcnt(6) [B(t) done].
//      B frag == global chunk quad*16 (swizzle involution cancels) ->
//      value-identical math. TILE/reduce/epilogue/XCD-swizzle verbatim.

typedef short s16x8 __attribute__((ext_vector_type(8)));   // 8 bf16
typedef float f32x4 __attribute__((ext_vector_type(4)));

#define BATCH 8192
#define IN_F  512
#define OUT_F 512
#define NB    8            // GRID_SIZE + SPLINE_ORDER
#define KKTOT (IN_F * NB)  // 4096
#define ROWB  (KKTOT * 2)  // 8192 B per row of Abf / BtT
#define NPH   64           // phases per K-group (2048 k / 32)

__device__ __forceinline__ uint32_t f2bf(float f) {
    union { float f; uint32_t u; } v; v.f = f;
    return (v.u + 0x7FFFu + ((v.u >> 16) & 1u)) >> 16;   // RNE bf16
}

__device__ __forceinline__ uint32_t bf16bits(float a) {
    __hip_bfloat16 h = __float2bfloat16(a);               // RNE
    union { __hip_bfloat16 h; unsigned short u; } c; c.h = h;
    return (uint32_t)c.u;
}

// 8 basis values for one x, packed bf16 into 16 bytes. Verified R0-R13.
__device__ __forceinline__ uint4 bspline_pack(float xraw) {
    float e  = __expf(2.0f * xraw);
    float xn = 1.0f - 2.0f / (e + 1.0f);          // tanh
    float u  = __fmaf_rn(xn, 2.5f, 5.5f);
    float fj = floorf(u);
    fj = fminf(fmaxf(fj, 3.0f), 7.0f);
    float t  = u - fj;
    float omt = 1.0f - t;
    float t2 = t * t;
    float t3 = t2 * t;
    const float s = 0.16666666666666666f;
    float w0 = s * omt * omt * omt;
    float w3 = s * t3;
    float w1 = s * __fmaf_rn(3.0f, t3, __fmaf_rn(-6.0f, t2, 4.0f));
    float w2 = 1.0f - w0 - w1 - w3;
    uint64_t packed = (uint64_t)(bf16bits(w0) | (bf16bits(w1) << 16))
                    | ((uint64_t)(bf16bits(w2) | (bf16bits(w3) << 16)) << 32);
    int sh = ((int)fj - 3) * 16;
    uint64_t lo, hi;
    if (sh == 0)      { lo = packed;       hi = 0ull; }
    else if (sh < 64) { lo = packed << sh; hi = packed >> (64 - sh); }
    else              { lo = 0ull;         hi = packed; }
    return make_uint4((uint32_t)lo, (uint32_t)(lo >> 32),
                      (uint32_t)hi, (uint32_t)(hi >> 32));
}

// Merged prep: blocks [0,1024) build BtT; blocks [1024,5120) build Abf.
// Verified R11-R13.
__global__ __launch_bounds__(256)
void prep_all(const float* __restrict__ X, const float* __restrict__ C,
              unsigned short* __restrict__ BtT, unsigned short* __restrict__ Abf) {
    if (blockIdx.x < 1024) {
        int t = blockIdx.x * 256 + threadIdx.x;
        int o = t & (OUT_F - 1);
        int i = t >> 9;
        const float4* src = (const float4*)(C + ((size_t)i * OUT_F + o) * NB);
        float4 c0 = src[0];
        float4 c1 = src[1];
        uint4 val;
        val.x = f2bf(c0.x) | (f2bf(c0.y) << 16);
        val.y = f2bf(c0.z) | (f2bf(c0.w) << 16);
        val.z = f2bf(c1.x) | (f2bf(c1.y) << 16);
        val.w = f2bf(c1.z) | (f2bf(c1.w) << 16);
        *(uint4*)(BtT + (size_t)o * KKTOT + (size_t)i * NB) = val;
    } else {
        int t  = (blockIdx.x - 1024) * 256 + threadIdx.x;  // 0..1,048,575
        int b  = t >> 7;
        int ip = t & 127;
        float4 xv = *(const float4*)(X + (size_t)b * IN_F + ip * 4);
        uint4 p0 = bspline_pack(xv.x);
        uint4 p1 = bspline_pack(xv.y);
        uint4 p2 = bspline_pack(xv.z);
        uint4 p3 = bspline_pack(xv.w);
        unsigned short* dst = Abf + (size_t)b * KKTOT + ip * 32;
        *(uint4*)(dst)      = p0;
        *(uint4*)(dst + 8)  = p1;
        *(uint4*)(dst + 16) = p2;
        *(uint4*)(dst + 24) = p3;
    }
}

__device__ __forceinline__ void gload_lds16(const void* g, void* l) {
    __builtin_amdgcn_global_load_lds(
        (const __attribute__((address_space(1))) uint32_t*)g,
        (__attribute__((address_space(3))) uint32_t*)l, 16, 0, 0);
}

// 128x128 block, 512 threads. Waves 0-3: k in [0,2048); 4-7: [2048,4096).
// Wave = 64x64 output (rm=cn=4). A: LDS, 4 bufs x 8 KB per group, staged 2
// ahead via global_load_lds (swizzled, verified R11-R13). B: per-wave
// global->reg, double-buffered, 1 phase ahead.
__global__ __launch_bounds__(512, 2)
void kan_gemm_mat3(const unsigned short* __restrict__ Abf,
                   const unsigned short* __restrict__ BtT,
                   float* __restrict__ Out) {
    __shared__ uint4 smem4[4096];                 // 64 KB = 4 bufs x 2 grp x 8 KB
    char* smem = (char*)smem4;

    const int tid    = threadIdx.x;
    const int lane   = tid & 63;
    const int wv     = tid >> 6;     // 0..7
    const int gg     = wv >> 2;      // K-group
    const int w      = wv & 3;       // wave within group
    const int wr     = w >> 1;       // 64-row half
    const int wc     = w & 1;        // 64-col half
    const int lane16 = lane & 15;
    const int quad   = lane >> 4;

    // XCD swizzle (verified R11: FETCH 135->49 MB)
    const int work = (blockIdx.x & 7) * 32 + (blockIdx.x >> 3);
    const int row0 = (work >> 2) * 128;
    const int col0 = (work & 3) * 128;

    // ---- A stage source addressing (pre-swizzled global; verified R11-13)
    const int Cchunk = (lane & 3) ^ ((lane >> 3) & 3);
    const int R0 = w * 32 + (lane >> 2);
    const size_t gk = (size_t)gg * 4096;
    const char* srcA0 = (const char*)Abf + (size_t)(row0 + R0) * ROWB + gk + Cchunk * 16;
    const char* srcA1 = srcA0 + (size_t)16 * ROWB;

    // ---- A fragment read addressing (verified R11-13)
    const int sx = (quad ^ ((lane16 >> 1) & 3)) << 4;
    const int abase = (wr * 64 + lane16) * 64 + sx;

    // ---- B direct global addressing: col = col0 + wc*64 + cn*16 + lane16,
    // byte = col*ROWB + gk + t*64 + quad*16 (involution cancels: chunk=quad)
    const char* bbaseg = (const char*)BtT
        + (size_t)(col0 + wc * 64 + lane16) * ROWB + gk + quad * 16;
    const char* bp0 = bbaseg;
    const char* bp1 = bbaseg + (size_t)16 * ROWB;
    const char* bp2 = bbaseg + (size_t)32 * ROWB;
    const char* bp3 = bbaseg + (size_t)48 * ROWB;

    f32x4 acc[4][4] = {};
    s16x8 bA0, bA1, bA2, bA3;        // B regs, even phases
    s16x8 bB0, bB1, bB2, bB3;        // B regs, odd phases

#define STAGE_A(B_, T_)                                                       \
    do {                                                                      \
        const size_t toff = (size_t)(T_) * 64;                                \
        char* la = smem + (B_) * 16384 + gg * 8192 + w * 2048;                \
        gload_lds16(srcA0 + toff, la);                                        \
        gload_lds16(srcA1 + toff, la + 1024);                                 \
    } while (0)

#define LOADB(R0_, R1_, R2_, R3_, T_)                                         \
    do {                                                                      \
        const size_t toff = (size_t)(T_) * 64;                                \
        R0_ = *(const s16x8*)(bp0 + toff);                                    \
        R1_ = *(const s16x8*)(bp1 + toff);                                    \
        R2_ = *(const s16x8*)(bp2 + toff);                                    \
        R3_ = *(const s16x8*)(bp3 + toff);                                    \
    } while (0)

#define TILE(B_, F0_, F1_, F2_, F3_)                                          \
    do {                                                                      \
        const char* ab = smem + (B_) * 16384 + gg * 8192;                     \
        s16x8 af0 = *(const s16x8*)(ab + abase);                              \
        s16x8 af1 = *(const s16x8*)(ab + abase + 1024);                       \
        s16x8 af2 = *(const s16x8*)(ab + abase + 2048);                       \
        s16x8 af3 = *(const s16x8*)(ab + abase + 3072);                       \
        __builtin_amdgcn_s_setprio(1);                                        \
        acc[0][0] = __builtin_amdgcn_mfma_f32_16x16x32_bf16(af0, F0_, acc[0][0], 0, 0, 0); \
        acc[0][1] = __builtin_amdgcn_mfma_f32_16x16x32_bf16(af0, F1_, acc[0][1], 0, 0, 0); \
        acc[0][2] = __builtin_amdgcn_mfma_f32_16x16x32_bf16(af0, F2_, acc[0][2], 0, 0, 0); \
        acc[0][3] = __builtin_amdgcn_mfma_f32_16x16x32_bf16(af0, F3_, acc[0][3], 0, 0, 0); \
        acc[1][0] = __builtin_amdgcn_mfma_f32_16x16x32_bf16(af1, F0_, acc[1][0], 0, 0, 0); \
        acc[1][1] = __builtin_amdgcn_mfma_f32_16x16x32_bf16(af1, F1_, acc[1][1], 0, 0, 0); \
        acc[1][2] = __builtin_amdgcn_mfma_f32_16x16x32_bf16(af1, F2_, acc[1][2], 0, 0, 0); \
        acc[1][3] = __builtin_amdgcn_mfma_f32_16x16x32_bf16(af1, F3_, acc[1][3], 0, 0, 0); \
        acc[2][0] = __builtin_amdgcn_mfma_f32_16x16x32_bf16(af2, F0_, acc[2][0], 0, 0, 0); \
        acc[2][1] = __builtin_amdgcn_mfma_f32_16x16x32_bf16(af2, F1_, acc[2][1], 0, 0, 0); \
        acc[2][2] = __builtin_amdgcn_mfma_f32_16x16x32_bf16(af2, F2_, acc[2][2], 0, 0, 0); \
        acc[2][3] = __builtin_amdgcn_mfma_f32_16x16x32_bf16(af2, F3_, acc[2][3], 0, 0, 0); \
        acc[3][0] = __builtin_amdgcn_mfma_f32_16x16x32_bf16(af3, F0_, acc[3][0], 0, 0, 0); \
        acc[3][1] = __builtin_amdgcn_mfma_f32_16x16x32_bf16(af3, F1_, acc[3][1], 0, 0, 0); \
        acc[3][2] = __builtin_amdgcn_mfma_f32_16x16x32_bf16(af3, F2_, acc[3][2], 0, 0, 0); \
        acc[3][3] = __builtin_amdgcn_mfma_f32_16x16x32_bf16(af3, F3_, acc[3][3], 0, 0, 0); \
        __builtin_amdgcn_s_setprio(0);                                        \
    } while (0)

// Steady phase: top vmcnt(6) [outstanding = A(t+1):2 + B(t):4; drains own
// A(t) -- required BEFORE barrier for cross-wave A visibility]; barrier;
// issue A(t+2), B(t+1); vmcnt(6) [drains B(t) (+A(t+1), harmless)];
// sched_barrier pins issues above the MFMA block; TILE(t).
// A-buf WAR: writer t+2 vs last reader t-2: 2 barriers apart.
#define PHASE(B_, SB_, T_, CUR0,CUR1,CUR2,CUR3, NXT0,NXT1,NXT2,NXT3)          \
    do {                                                                      \
        asm volatile("s_waitcnt vmcnt(6)" ::: "memory");                      \
        __builtin_amdgcn_s_barrier();                                         \
        STAGE_A(SB_, (T_) + 2);                                               \
        LOADB(NXT0, NXT1, NXT2, NXT3, (T_) + 1);                              \
        asm volatile("s_waitcnt vmcnt(6)" ::: "memory");                      \
        __builtin_amdgcn_sched_barrier(0);                                    \
        TILE(B_, CUR0, CUR1, CUR2, CUR3);                                     \
    } while (0)

    // prologue: A(0),A(1) staged; B(0) loaded. Outstanding = 2+2+4 = 8.
    STAGE_A(0, 0);
    STAGE_A(1, 1);
    LOADB(bA0, bA1, bA2, bA3, 0);

    for (int t = 0; t < NPH - 4; t += 4) {        // phases 0..59
        PHASE(0, 2, t + 0, bA0,bA1,bA2,bA3, bB0,bB1,bB2,bB3);
        PHASE(1, 3, t + 1, bB0,bB1,bB2,bB3, bA0,bA1,bA2,bA3);
        PHASE(2, 0, t + 2, bA0,bA1,bA2,bA3, bB0,bB1,bB2,bB3);
        PHASE(3, 1, t + 3, bB0,bB1,bB2,bB3, bA0,bA1,bA2,bA3);
    }
    // tail: phases 60..63
    PHASE(0, 2, 60, bA0,bA1,bA2,bA3, bB0,bB1,bB2,bB3);   // stages A(62)
    PHASE(1, 3, 61, bB0,bB1,bB2,bB3, bA0,bA1,bA2,bA3);   // stages A(63)
    // phase 62: no stage; load B(63); need B(62) done -> vmcnt(4)
    asm volatile("s_waitcnt vmcnt(6)" ::: "memory");
    __builtin_amdgcn_s_barrier();
    LOADB(bB0, bB1, bB2, bB3, 63);
    asm volatile("s_waitcnt vmcnt(4)" ::: "memory");
    __builtin_amdgcn_sched_barrier(0);
    TILE(2, bA0, bA1, bA2, bA3);
    // phase 63: need A(63) (already drained) + B(63)
    asm volatile("s_waitcnt vmcnt(4)" ::: "memory");
    __builtin_amdgcn_s_barrier();
    asm volatile("s_waitcnt vmcnt(0)" ::: "memory");
    __builtin_amdgcn_sched_barrier(0);
    TILE(3, bB0, bB1, bB2, bB3);
#undef PHASE
#undef TILE
#undef LOADB
#undef STAGE_A

    // ---- cross-group K reduce via LDS (conflict-free lane-major; 64 KB)
    __builtin_amdgcn_s_barrier();                 // all TILE reads done
    f32x4* red = (f32x4*)smem + (size_t)w * 1024; // 16 KB per wave pair
    if (gg == 1) {
        #pragma unroll
        for (int rm = 0; rm < 4; ++rm)
            #pragma unroll
            for (int cn = 0; cn < 4; ++cn)
                red[(rm * 4 + cn) * 64 + lane] = acc[rm][cn];
    }
    __builtin_amdgcn_s_barrier();
    if (gg == 0) {
        #pragma unroll
        for (int rm = 0; rm < 4; ++rm)
            #pragma unroll
            for (int cn = 0; cn < 4; ++cn)
                acc[rm][cn] += red[(rm * 4 + cn) * 64 + lane];
        // Epilogue: C/D layout col=lane&15, row=quad*4+reg (verified)
        #pragma unroll
        for (int rm = 0; rm < 4; ++rm) {
            const int orow = row0 + wr * 64 + rm * 16 + quad * 4;
            #pragma unroll
            for (int cn = 0; cn < 4; ++cn) {
                float* dst = Out + (size_t)orow * OUT_F
                           + col0 + wc * 64 + cn * 16 + lane16;
                #pragma unroll
                for (int r = 0; r < 4; ++r)
                    dst[(size_t)r * OUT_F] = acc[rm][cn][r];
            }
        }
    }
}

extern "C" void kernel_launch(void* const* d_in, const int* in_sizes, int n_in,
                              void* d_out, int out_size, void* d_ws, size_t ws_size,
                              hipStream_t stream) {
    const float* X  = (const float*)d_in[0];   // (8192, 512) f32
    const float* C  = (const float*)d_in[1];   // (512, 512, 8) f32
    float* Out = (float*)d_out;                // (8192, 512) f32

    unsigned short* BtT = (unsigned short*)d_ws;                                      // 4 MB
    unsigned short* Abf = (unsigned short*)((char*)d_ws + (size_t)OUT_F * KKTOT * 2); // 64 MB

    prep_all<<<dim3(5120), 256, 0, stream>>>(X, C, BtT, Abf);
    kan_gemm_mat3<<<dim3(256), 512, 0, stream>>>(Abf, BtT, Out);
}

// Round 14
// 128.488 us; speedup vs baseline: 1.3615x; 1.3615x over previous
//
#include <hip/hip_runtime.h>
#include <hip/hip_bf16.h>
#include <stdint.h>

// BSpline KAN layer: out[b,o] = sum_{i,k} bases(tanh(x[b,i]))[k] * C[i,o,k]
// == GEMM M=8192, N=512, K=4096 with generated A. bf16 MFMA path.
// History:
//  R10 57.4us materialized A. R12 46.5us: counted-vmcnt 4-deep BK32 (+25%).
//  R13 48.3us: depth-2 double-barrier schedule (grid=256 -> 2blocks/CU was
//      impossible; lesson: occupancy = min(grid/CU, resources)).
//  R14 88.6us REGRESSED: per-wave direct-B = 4x line traffic + in-order
//      vmcnt retiring fresh stages -> both operands stay LDS-staged.
//  Model: port floor 65k cyc (27us) + MFMA 40k + residual ~730-800 cyc/phase
//      x 64 phases. Residual is per-PHASE (sync/jitter), not per-byte.
//  R15: BK 32->64: 32 phases, same total port/MFMA demand -> residual
//      halves. Depth 2 (2grp x 2buf x 32KB = 128KB, R12-proven size),
//      R13's verified [vmcnt(8)|barrier|TILE|barrier|STAGE] schedule.
//      128B-row 8-slot XOR swizzle = R8's verified constants verbatim.
//      Accumulation order unchanged -> bit-identical output (absmax 0.03125).
//  R16: resubmit — R15 bench was an infra failure (container acquire, 3rd
//      of session; R2/R3 pattern, that kernel later ran clean). Re-audit:
//      stage/read algebra re-derived OK, vmcnt ledger OK, bounds OK
//      (max in-row byte 8176 < 8192), ~110 VGPR under (512,1) cap.

typedef short s16x8 __attribute__((ext_vector_type(8)));   // 8 bf16
typedef float f32x4 __attribute__((ext_vector_type(4)));

#define BATCH 8192
#define IN_F  512
#define OUT_F 512
#define NB    8            // GRID_SIZE + SPLINE_ORDER
#define KKTOT (IN_F * NB)  // 4096
#define ROWB  (KKTOT * 2)  // 8192 B per row of Abf / BtT
#define NPH   32           // phases per K-group (2048 k / 64)

__device__ __forceinline__ uint32_t f2bf(float f) {
    union { float f; uint32_t u; } v; v.f = f;
    return (v.u + 0x7FFFu + ((v.u >> 16) & 1u)) >> 16;   // RNE bf16
}

__device__ __forceinline__ uint32_t bf16bits(float a) {
    __hip_bfloat16 h = __float2bfloat16(a);               // RNE
    union { __hip_bfloat16 h; unsigned short u; } c; c.h = h;
    return (uint32_t)c.u;
}

// 8 basis values for one x, packed bf16 into 16 bytes. Verified R0-R14.
__device__ __forceinline__ uint4 bspline_pack(float xraw) {
    float e  = __expf(2.0f * xraw);
    float xn = 1.0f - 2.0f / (e + 1.0f);          // tanh
    float u  = __fmaf_rn(xn, 2.5f, 5.5f);
    float fj = floorf(u);
    fj = fminf(fmaxf(fj, 3.0f), 7.0f);
    float t  = u - fj;
    float omt = 1.0f - t;
    float t2 = t * t;
    float t3 = t2 * t;
    const float s = 0.16666666666666666f;
    float w0 = s * omt * omt * omt;
    float w3 = s * t3;
    float w1 = s * __fmaf_rn(3.0f, t3, __fmaf_rn(-6.0f, t2, 4.0f));
    float w2 = 1.0f - w0 - w1 - w3;
    uint64_t packed = (uint64_t)(bf16bits(w0) | (bf16bits(w1) << 16))
                    | ((uint64_t)(bf16bits(w2) | (bf16bits(w3) << 16)) << 32);
    int sh = ((int)fj - 3) * 16;
    uint64_t lo, hi;
    if (sh == 0)      { lo = packed;       hi = 0ull; }
    else if (sh < 64) { lo = packed << sh; hi = packed >> (64 - sh); }
    else              { lo = 0ull;         hi = packed; }
    return make_uint4((uint32_t)lo, (uint32_t)(lo >> 32),
                      (uint32_t)hi, (uint32_t)(hi >> 32));
}

// Merged prep: blocks [0,1024) build BtT; blocks [1024,5120) build Abf.
// Verified R11-R14.
__global__ __launch_bounds__(256)
void prep_all(const float* __restrict__ X, const float* __restrict__ C,
              unsigned short* __restrict__ BtT, unsigned short* __restrict__ Abf) {
    if (blockIdx.x < 1024) {
        int t = blockIdx.x * 256 + threadIdx.x;
        int o = t & (OUT_F - 1);
        int i = t >> 9;
        const float4* src = (const float4*)(C + ((size_t)i * OUT_F + o) * NB);
        float4 c0 = src[0];
        float4 c1 = src[1];
        uint4 val;
        val.x = f2bf(c0.x) | (f2bf(c0.y) << 16);
        val.y = f2bf(c0.z) | (f2bf(c0.w) << 16);
        val.z = f2bf(c1.x) | (f2bf(c1.y) << 16);
        val.w = f2bf(c1.z) | (f2bf(c1.w) << 16);
        *(uint4*)(BtT + (size_t)o * KKTOT + (size_t)i * NB) = val;
    } else {
        int t  = (blockIdx.x - 1024) * 256 + threadIdx.x;  // 0..1,048,575
        int b  = t >> 7;
        int ip = t & 127;
        float4 xv = *(const float4*)(X + (size_t)b * IN_F + ip * 4);
        uint4 p0 = bspline_pack(xv.x);
        uint4 p1 = bspline_pack(xv.y);
        uint4 p2 = bspline_pack(xv.z);
        uint4 p3 = bspline_pack(xv.w);
        unsigned short* dst = Abf + (size_t)b * KKTOT + ip * 32;
        *(uint4*)(dst)      = p0;
        *(uint4*)(dst + 8)  = p1;
        *(uint4*)(dst + 16) = p2;
        *(uint4*)(dst + 24) = p3;
    }
}

__device__ __forceinline__ void gload_lds16(const void* g, void* l) {
    __builtin_amdgcn_global_load_lds(
        (const __attribute__((address_space(1))) uint32_t*)g,
        (__attribute__((address_space(3))) uint32_t*)l, 16, 0, 0);
}

// 128x128 block, 512 threads. Waves 0-3: k in [0,2048); 4-7: [2048,4096).
// Wave = 64x64 (rm=cn=4). BK=64 (128 B per row per phase), 32 phases.
// 2 bufs x 2 groups x 32 KB = 128 KB, staged 1 ahead, counted vmcnt(8).
// LDS tile layout (R8-verified 8-slot involution): row R, slot S holds
// global k-chunk S ^ (R&7); read chunk (ks*4+quad) ^ (lane16&7).
__global__ __launch_bounds__(512, 1)
void kan_gemm_mat2(const unsigned short* __restrict__ Abf,
                   const unsigned short* __restrict__ BtT,
                   float* __restrict__ Out) {
    __shared__ uint4 smem4[8192];                 // 128 KB
    char* smem = (char*)smem4;

    const int tid    = threadIdx.x;
    const int lane   = tid & 63;
    const int wv     = tid >> 6;     // 0..7
    const int gg     = wv >> 2;      // K-group
    const int w      = wv & 3;       // wave within group
    const int wr     = w >> 1;       // 64-row half
    const int wc     = w & 1;        // 64-col half
    const int lane16 = lane & 15;
    const int quad   = lane >> 4;

    // XCD swizzle (verified R11: FETCH 135->49 MB)
    const int work = (blockIdx.x & 7) * 32 + (blockIdx.x >> 3);
    const int row0 = (work >> 2) * 128;
    const int col0 = (work & 3) * 128;

    // ---- stage source addressing (pre-swizzled global; R8-verified) ----
    // instr n of wave w covers rows w*32 + n*8 + (lane>>3), slot lane&7,
    // global chunk = (lane&7) ^ (row&7) = (lane&7) ^ ((lane>>3)&7).
    const int Cchunk = (lane & 7) ^ ((lane >> 3) & 7);
    const int R0 = w * 32 + (lane >> 3);
    const size_t gk = (size_t)gg * 4096;          // K-group byte offset in row
    const char* srcA0 = (const char*)Abf + (size_t)(row0 + R0) * ROWB + gk + Cchunk * 16;
    const char* srcB0 = (const char*)BtT + (size_t)(col0 + R0) * ROWB + gk + Cchunk * 16;

    // ---- fragment read addressing (R8-verified algebra) ----
    // row/col = (wr|wc)*64 + f*16 + lane16; chunk (ks*4+quad)^(row&7),
    // row&7 == lane16&7 (all other offsets are 0 mod 8).
    const int sx0 = ((quad)     ^ (lane16 & 7)) << 4;
    const int sx1 = ((4 + quad) ^ (lane16 & 7)) << 4;
    const int abase = (wr * 64 + lane16) * 128;
    const int bbase = (wc * 64 + lane16) * 128;

    f32x4 acc[4][4] = {};

#define STAGE(B_, T_)                                                         \
    do {                                                                      \
        const size_t toff = (size_t)(T_) * 128;                               \
        char* la = smem + (gg * 2 + (B_)) * 32768 + w * 4096;                 \
        _Pragma("unroll")                                                     \
        for (int n = 0; n < 4; ++n) {                                         \
            gload_lds16(srcA0 + (size_t)n * 8 * ROWB + toff, la + n * 1024);  \
            gload_lds16(srcB0 + (size_t)n * 8 * ROWB + toff,                  \
                        la + 16384 + n * 1024);                               \
        }                                                                     \
    } while (0)

#define HALF(AB_, BB_, SX_)                                                   \
    do {                                                                      \
        s16x8 af0 = *(const s16x8*)((AB_) + abase + 0    + (SX_));            \
        s16x8 af1 = *(const s16x8*)((AB_) + abase + 2048 + (SX_));            \
        s16x8 af2 = *(const s16x8*)((AB_) + abase + 4096 + (SX_));            \
        s16x8 af3 = *(const s16x8*)((AB_) + abase + 6144 + (SX_));            \
        s16x8 bf0 = *(const s16x8*)((BB_) + bbase + 0    + (SX_));            \
        s16x8 bf1 = *(const s16x8*)((BB_) + bbase + 2048 + (SX_));            \
        s16x8 bf2 = *(const s16x8*)((BB_) + bbase + 4096 + (SX_));            \
        s16x8 bf3 = *(const s16x8*)((BB_) + bbase + 6144 + (SX_));            \
        __builtin_amdgcn_s_setprio(1);                                        \
        acc[0][0] = __builtin_amdgcn_mfma_f32_16x16x32_bf16(af0, bf0, acc[0][0], 0, 0, 0); \
        acc[0][1] = __builtin_amdgcn_mfma_f32_16x16x32_bf16(af0, bf1, acc[0][1], 0, 0, 0); \
        acc[0][2] = __builtin_amdgcn_mfma_f32_16x16x32_bf16(af0, bf2, acc[0][2], 0, 0, 0); \
        acc[0][3] = __builtin_amdgcn_mfma_f32_16x16x32_bf16(af0, bf3, acc[0][3], 0, 0, 0); \
        acc[1][0] = __builtin_amdgcn_mfma_f32_16x16x32_bf16(af1, bf0, acc[1][0], 0, 0, 0); \
        acc[1][1] = __builtin_amdgcn_mfma_f32_16x16x32_bf16(af1, bf1, acc[1][1], 0, 0, 0); \
        acc[1][2] = __builtin_amdgcn_mfma_f32_16x16x32_bf16(af1, bf2, acc[1][2], 0, 0, 0); \
        acc[1][3] = __builtin_amdgcn_mfma_f32_16x16x32_bf16(af1, bf3, acc[1][3], 0, 0, 0); \
        acc[2][0] = __builtin_amdgcn_mfma_f32_16x16x32_bf16(af2, bf0, acc[2][0], 0, 0, 0); \
        acc[2][1] = __builtin_amdgcn_mfma_f32_16x16x32_bf16(af2, bf1, acc[2][1], 0, 0, 0); \
        acc[2][2] = __builtin_amdgcn_mfma_f32_16x16x32_bf16(af2, bf2, acc[2][2], 0, 0, 0); \
        acc[2][3] = __builtin_amdgcn_mfma_f32_16x16x32_bf16(af2, bf3, acc[2][3], 0, 0, 0); \
        acc[3][0] = __builtin_amdgcn_mfma_f32_16x16x32_bf16(af3, bf0, acc[3][0], 0, 0, 0); \
        acc[3][1] = __builtin_amdgcn_mfma_f32_16x16x32_bf16(af3, bf1, acc[3][1], 0, 0, 0); \
        acc[3][2] = __builtin_amdgcn_mfma_f32_16x16x32_bf16(af3, bf2, acc[3][2], 0, 0, 0); \
        acc[3][3] = __builtin_amdgcn_mfma_f32_16x16x32_bf16(af3, bf3, acc[3][3], 0, 0, 0); \
        __builtin_amdgcn_s_setprio(0);                                        \
    } while (0)

#define TILE(B_)                                                              \
    do {                                                                      \
        const char* ab = smem + (gg * 2 + (B_)) * 32768;                      \
        const char* bb = ab + 16384;                                          \
        HALF(ab, bb, sx0);                                                    \
        HALF(ab, bb, sx1);                                                    \
    } while (0)

    // prologue: 2 tiles in flight (16 loads/wave)
    STAGE(0, 0);
    STAGE(1, 1);

    // phase t: vmcnt(8) [own stage(t) done, stage(t+1) still flying] ->
    // barrier -> TILE(t) -> barrier [all reads of buf done] -> STAGE(t+2).
    for (int t = 0; t < NPH - 2; t += 2) {
        asm volatile("s_waitcnt vmcnt(8)" ::: "memory");
        __builtin_amdgcn_s_barrier();
        TILE(0);
        __builtin_amdgcn_s_barrier();
        STAGE(0, t + 2);
        asm volatile("s_waitcnt vmcnt(8)" ::: "memory");
        __builtin_amdgcn_s_barrier();
        TILE(1);
        __builtin_amdgcn_s_barrier();
        STAGE(1, t + 3);
    }
    // tail: phases 30,31 (no more stages)
    asm volatile("s_waitcnt vmcnt(8)" ::: "memory");
    __builtin_amdgcn_s_barrier();
    TILE(0);
    asm volatile("s_waitcnt vmcnt(0)" ::: "memory");
    __builtin_amdgcn_s_barrier();
    TILE(1);
#undef TILE
#undef HALF
#undef STAGE

    // ---- cross-group K reduce via LDS (conflict-free lane-major) ----
    __builtin_amdgcn_s_barrier();                 // all TILE reads done
    f32x4* red = (f32x4*)smem + (size_t)w * 1024; // 16 KB per wave pair
    if (gg == 1) {
        #pragma unroll
        for (int rm = 0; rm < 4; ++rm)
            #pragma unroll
            for (int cn = 0; cn < 4; ++cn)
                red[(rm * 4 + cn) * 64 + lane] = acc[rm][cn];
    }
    __builtin_amdgcn_s_barrier();
    if (gg == 0) {
        #pragma unroll
        for (int rm = 0; rm < 4; ++rm)
            #pragma unroll
            for (int cn = 0; cn < 4; ++cn)
                acc[rm][cn] += red[(rm * 4 + cn) * 64 + lane];
        // Epilogue: C/D layout col=lane&15, row=quad*4+reg (verified)
        #pragma unroll
        for (int rm = 0; rm < 4; ++rm) {
            const int orow = row0 + wr * 64 + rm * 16 + quad * 4;
            #pragma unroll
            for (int cn = 0; cn < 4; ++cn) {
                float* dst = Out + (size_t)orow * OUT_F
                           + col0 + wc * 64 + cn * 16 + lane16;
                #pragma unroll
                for (int r = 0; r < 4; ++r)
                    dst[(size_t)r * OUT_F] = acc[rm][cn][r];
            }
        }
    }
}

extern "C" void kernel_launch(void* const* d_in, const int* in_sizes, int n_in,
                              void* d_out, int out_size, void* d_ws, size_t ws_size,
                              hipStream_t stream) {
    const float* X  = (const float*)d_in[0];   // (8192, 512) f32
    const float* C  = (const float*)d_in[1];   // (512, 512, 8) f32
    float* Out = (float*)d_out;                // (8192, 512) f32

    unsigned short* BtT = (unsigned short*)d_ws;                                      // 4 MB
    unsigned short* Abf = (unsigned short*)((char*)d_ws + (size_t)OUT_F * KKTOT * 2); // 64 MB

    prep_all<<<dim3(5120), 256, 0, stream>>>(X, C, BtT, Abf);
    kan_gemm_mat2<<<dim3(256), 512, 0, stream>>>(Abf, BtT, Out);
}